// Round 1
// baseline (600.103 us; speedup 1.0000x reference)
//
#include <hip/hip_runtime.h>

// Problem constants (from reference): N samples, NC classes, FD feature dim.
#define NS 32768
#define NC 395
#define FD 512

// Static device accumulators — avoids relying on ws_size; zeroed every call.
__device__ float g_counts[NC];
__device__ float g_sum1[NC * FD];
__device__ float g_sum2[NC * FD];

__global__ void zero_kernel(float* __restrict__ out) {
    int gid = blockIdx.x * blockDim.x + threadIdx.x;
    if (gid == 0) out[0] = 0.0f;
    if (gid < NC) g_counts[gid] = 0.0f;
    const int total = NC * FD;
    for (int i = gid; i < total; i += gridDim.x * blockDim.x) {
        g_sum1[i] = 0.0f;
        g_sum2[i] = 0.0f;
    }
}

// One thread per (sample, dim-quad). Consecutive threads cover consecutive
// quads of one sample -> fully coalesced float4 loads (16 B/lane).
__global__ void sum_kernel(const float4* __restrict__ m1,
                           const float4* __restrict__ m2,
                           const int* __restrict__ targets) {
    int gid = blockIdx.x * blockDim.x + threadIdx.x;  // 0 .. NS*128-1
    int i = gid >> 7;   // sample index
    int q = gid & 127;  // quad index within the 512-dim row
    int t = targets[i]; // broadcast across 128 consecutive threads (L1 hit)
    float4 a = m1[gid];
    float4 b = m2[gid];
    float* s1 = &g_sum1[t * FD + q * 4];
    float* s2 = &g_sum2[t * FD + q * 4];
    atomicAdd(s1 + 0, a.x);
    atomicAdd(s1 + 1, a.y);
    atomicAdd(s1 + 2, a.z);
    atomicAdd(s1 + 3, a.w);
    atomicAdd(s2 + 0, b.x);
    atomicAdd(s2 + 1, b.y);
    atomicAdd(s2 + 2, b.z);
    atomicAdd(s2 + 3, b.w);
    if (q == 0) atomicAdd(&g_counts[t], 1.0f);
}

__device__ __forceinline__ float smooth_l1(float d) {
    d = fabsf(d);
    return d < 1.0f ? 0.5f * d * d : d - 0.5f;
}

// One thread per (class, dim) element; weight by raw count (empty class -> 0).
__global__ void loss_kernel(const float* __restrict__ centers,
                            float* __restrict__ out) {
    int gid = blockIdx.x * blockDim.x + threadIdx.x;
    float val = 0.0f;
    if (gid < NC * FD) {
        int c = gid >> 9;  // FD == 512
        float cnt = g_counts[c];
        if (cnt > 0.0f) {
            float ctr = centers[gid];
            float inv = 1.0f / cnt;
            float f1 = smooth_l1(g_sum1[gid] * inv - ctr);
            float f2 = smooth_l1(g_sum2[gid] * inv - ctr);
            val = cnt * (f1 + f2);
        }
    }
    // wave-64 shuffle reduction
    for (int off = 32; off > 0; off >>= 1)
        val += __shfl_down(val, off, 64);
    __shared__ float wsum[4];
    int lane = threadIdx.x & 63;
    int wid = threadIdx.x >> 6;
    if (lane == 0) wsum[wid] = val;
    __syncthreads();
    if (threadIdx.x == 0) {
        float s = wsum[0] + wsum[1] + wsum[2] + wsum[3];
        // mean over N*D elements; 1/(32768*512) == 2^-24 exactly.
        atomicAdd(out, s * 5.9604644775390625e-08f);
    }
}

extern "C" void kernel_launch(void* const* d_in, const int* in_sizes, int n_in,
                              void* d_out, int out_size, void* d_ws, size_t ws_size,
                              hipStream_t stream) {
    const float4* m1 = (const float4*)d_in[0];
    const float4* m2 = (const float4*)d_in[1];
    const float* centers = (const float*)d_in[2];
    const int* targets = (const int*)d_in[3];
    float* out = (float*)d_out;

    zero_kernel<<<790, 256, 0, stream>>>(out);
    sum_kernel<<<(NS * (FD / 4)) / 256, 256, 0, stream>>>(m1, m2, targets);
    loss_kernel<<<(NC * FD + 255) / 256, 256, 0, stream>>>(centers, out);
}

// Round 2
// 197.944 us; speedup vs baseline: 3.0317x; 3.0317x over previous
//
#include <hip/hip_runtime.h>

#define NS 32768
#define NC 395
#define FD 512
#define SPLITS 4

// Static device scratch (persistent, fully rewritten every call).
__device__ int   g_hist[NC];     // per-class counts
__device__ int   g_offs[NC];     // exclusive prefix offsets
__device__ int   g_cursor[NC];   // scatter cursors
__device__ float g_countsf[NC];  // counts as float for loss kernel
__device__ int   g_order[NS];    // sample indices sorted by class
// partial sums: [split][modality][class][dim]  (6.5 MB, every slot written)
__device__ float g_partial[SPLITS * 2 * NC * FD];

// ---------------------------------------------------------------------------
// K1: single block — zero out, histogram targets, prefix-scan, init cursors.
__global__ void hist_scan_kernel(const int* __restrict__ targets,
                                 float* __restrict__ out) {
    __shared__ int lhist[NC];
    __shared__ int sc[512];
    int t = threadIdx.x;          // block = 1024 threads
    for (int i = t; i < NC; i += 1024) lhist[i] = 0;
    __syncthreads();
    for (int i = t; i < NS; i += 1024) atomicAdd(&lhist[targets[i]], 1);
    __syncthreads();
    // inclusive Hillis-Steele scan over 512 slots (NC <= 512)
    if (t < 512) sc[t] = (t < NC) ? lhist[t] : 0;
    __syncthreads();
    for (int off = 1; off < 512; off <<= 1) {
        int v = 0;
        if (t < 512 && t >= off) v = sc[t - off];
        __syncthreads();
        if (t < 512) sc[t] += v;
        __syncthreads();
    }
    if (t < NC) {
        int cnt = lhist[t];
        int off = sc[t] - cnt;    // exclusive
        g_hist[t]    = cnt;
        g_offs[t]    = off;
        g_cursor[t]  = off;
        g_countsf[t] = (float)cnt;
    }
    if (t == 0) out[0] = 0.0f;
}

// ---------------------------------------------------------------------------
// K2: scatter sample indices into class-sorted order (32K atomics on 395 ctrs).
__global__ void scatter_kernel(const int* __restrict__ targets) {
    int i = blockIdx.x * blockDim.x + threadIdx.x;
    if (i < NS) {
        int pos = atomicAdd(&g_cursor[targets[i]], 1);
        g_order[pos] = i;
    }
}

// ---------------------------------------------------------------------------
__device__ __forceinline__ void f4add(float4& a, const float4 b) {
    a.x += b.x; a.y += b.y; a.z += b.z; a.w += b.w;
}

// K3: one block per (class, split). Threads 0-127: modality 1 quads;
// threads 128-255: modality 2 quads. Register accumulation, zero atomics.
__global__ void gather_sum_kernel(const float4* __restrict__ m1,
                                  const float4* __restrict__ m2) {
    int c = blockIdx.x >> 2;      // class
    int s = blockIdx.x & 3;       // split
    int tid = threadIdx.x;
    int m = tid >> 7;             // modality (wave-uniform)
    int q = tid & 127;            // float4 quad within the 512-dim row
    const float4* src = m ? m2 : m1;

    int start = g_offs[c];
    int n     = g_hist[c];
    int s0 = start + (n * s) / SPLITS;
    int s1 = start + (n * (s + 1)) / SPLITS;

    float4 a0 = make_float4(0.f, 0.f, 0.f, 0.f);
    float4 a1 = a0, a2 = a0, a3 = a0;

    __shared__ int sidx[256];
    for (int base = s0; base < s1; base += 256) {
        int nn = min(256, s1 - base);
        if (tid < nn) sidx[tid] = g_order[base + tid];
        __syncthreads();
        int j = 0;
        for (; j + 4 <= nn; j += 4) {
            int i0 = sidx[j], i1 = sidx[j + 1], i2 = sidx[j + 2], i3 = sidx[j + 3];
            float4 v0 = src[(size_t)i0 * 128 + q];
            float4 v1 = src[(size_t)i1 * 128 + q];
            float4 v2 = src[(size_t)i2 * 128 + q];
            float4 v3 = src[(size_t)i3 * 128 + q];
            f4add(a0, v0); f4add(a1, v1); f4add(a2, v2); f4add(a3, v3);
        }
        for (; j < nn; j++) {
            f4add(a0, src[(size_t)sidx[j] * 128 + q]);
        }
        __syncthreads();
    }
    f4add(a0, a1); f4add(a2, a3); f4add(a0, a2);

    // partial[s][m][c][q*4 ..]
    float4* dst = reinterpret_cast<float4*>(g_partial);
    dst[(((size_t)s * 2 + m) * NC + c) * 128 + q] = a0;
}

// ---------------------------------------------------------------------------
__device__ __forceinline__ float smooth_l1(float d) {
    d = fabsf(d);
    return d < 1.0f ? 0.5f * d * d : d - 0.5f;
}

// K4: combine partials, per-element SmoothL1 weighted by count, reduce.
__global__ void loss_kernel(const float* __restrict__ centers,
                            float* __restrict__ out) {
    int gid = blockIdx.x * blockDim.x + threadIdx.x;
    float val = 0.0f;
    if (gid < NC * FD) {
        int c = gid >> 9;  // FD == 512
        float cnt = g_countsf[c];
        if (cnt > 0.0f) {
            float sum1 = 0.0f, sum2 = 0.0f;
            #pragma unroll
            for (int s = 0; s < SPLITS; s++) {
                sum1 += g_partial[((s * 2 + 0) * NC) * FD + gid];
                sum2 += g_partial[((s * 2 + 1) * NC) * FD + gid];
            }
            float ctr = centers[gid];
            float inv = 1.0f / cnt;
            float f1 = smooth_l1(sum1 * inv - ctr);
            float f2 = smooth_l1(sum2 * inv - ctr);
            val = cnt * (f1 + f2);
        }
    }
    for (int off = 32; off > 0; off >>= 1)
        val += __shfl_down(val, off, 64);
    __shared__ float wsum[4];
    int lane = threadIdx.x & 63;
    int wid = threadIdx.x >> 6;
    if (lane == 0) wsum[wid] = val;
    __syncthreads();
    if (threadIdx.x == 0) {
        float s = wsum[0] + wsum[1] + wsum[2] + wsum[3];
        atomicAdd(out, s * 5.9604644775390625e-08f);  // 1/(N*D) = 2^-24
    }
}

extern "C" void kernel_launch(void* const* d_in, const int* in_sizes, int n_in,
                              void* d_out, int out_size, void* d_ws, size_t ws_size,
                              hipStream_t stream) {
    const float4* m1 = (const float4*)d_in[0];
    const float4* m2 = (const float4*)d_in[1];
    const float* centers = (const float*)d_in[2];
    const int* targets = (const int*)d_in[3];
    float* out = (float*)d_out;

    hist_scan_kernel<<<1, 1024, 0, stream>>>(targets, out);
    scatter_kernel<<<(NS + 255) / 256, 256, 0, stream>>>(targets);
    gather_sum_kernel<<<NC * SPLITS, 256, 0, stream>>>(m1, m2);
    loss_kernel<<<(NC * FD + 255) / 256, 256, 0, stream>>>(centers, out);
}

// Round 3
// 194.468 us; speedup vs baseline: 3.0859x; 1.0179x over previous
//
#include <hip/hip_runtime.h>

#define NS 32768
#define NC 395
#define FD 512
#define SPLITS 8
#define HB 128   // histogram blocks
#define HT 256   // histogram threads/block   (HB*HT == NS)

// Static device scratch — every slot rewritten each call (no cross-call state).
__device__ int   g_hist_part[HB * NC];  // per-block histograms (slabs)
__device__ int   g_hist[NC];
__device__ int   g_offs[NC];
__device__ int   g_cursor[NC];
__device__ float g_countsf[NC];
__device__ int   g_order[NS];           // sample idx sorted by class
// partial sums: [split][modality][class][dim]  (~13 MB, every slot written)
__device__ float g_partial[SPLITS * 2 * NC * FD];

// ---------------------------------------------------------------------------
// K1: per-block LDS histogram -> private slab (slab fully written, no pre-zero).
__global__ void hist_kernel(const int* __restrict__ targets) {
    __shared__ int lh[NC];
    int t = threadIdx.x;
    for (int i = t; i < NC; i += HT) lh[i] = 0;
    __syncthreads();
    atomicAdd(&lh[targets[blockIdx.x * HT + t]], 1);
    __syncthreads();
    int* slab = &g_hist_part[blockIdx.x * NC];
    for (int c = t; c < NC; c += HT) slab[c] = lh[c];
}

// ---------------------------------------------------------------------------
// K2: single block — reduce slabs (200 KB coalesced), scan, init, zero out.
__global__ void scan_kernel(float* __restrict__ out) {
    __shared__ int sc[512];
    int t = threadIdx.x;  // 512 threads
    int cnt = 0;
    if (t < NC) {
        #pragma unroll 4
        for (int p = 0; p < HB; p++) cnt += g_hist_part[p * NC + t];
    }
    sc[t] = (t < NC) ? cnt : 0;
    __syncthreads();
    // inclusive Hillis-Steele over 512 slots
    for (int off = 1; off < 512; off <<= 1) {
        int v = (t >= off) ? sc[t - off] : 0;
        __syncthreads();
        sc[t] += v;
        __syncthreads();
    }
    if (t < NC) {
        g_hist[t]    = cnt;
        g_offs[t]    = sc[t] - cnt;  // exclusive
        g_cursor[t]  = sc[t] - cnt;
        g_countsf[t] = (float)cnt;
    }
    if (t == 0) out[0] = 0.0f;
}

// ---------------------------------------------------------------------------
// K3: scatter sample indices into class-sorted order.
__global__ void scatter_kernel(const int* __restrict__ targets) {
    int i = blockIdx.x * blockDim.x + threadIdx.x;
    if (i < NS) {
        int pos = atomicAdd(&g_cursor[targets[i]], 1);
        g_order[pos] = i;
    }
}

// ---------------------------------------------------------------------------
__device__ __forceinline__ void f4add(float4& a, const float4 b) {
    a.x += b.x; a.y += b.y; a.z += b.z; a.w += b.w;
}

// K4: one block per (class, split). Threads 0-127: modality 1; 128-255: m2.
// Register accumulation, zero atomics, coalesced 1KB-per-wave row reads.
__global__ void gather_sum_kernel(const float4* __restrict__ m1,
                                  const float4* __restrict__ m2) {
    int c = blockIdx.x >> 3;      // class
    int s = blockIdx.x & 7;       // split
    int tid = threadIdx.x;
    int m = tid >> 7;             // modality (wave-uniform)
    int q = tid & 127;            // float4 quad within the 512-dim row
    const float4* src = m ? m2 : m1;

    int start = g_offs[c];
    int n     = g_hist[c];
    int s0 = start + (n * s) / SPLITS;
    int s1 = start + (n * (s + 1)) / SPLITS;

    float4 a0 = make_float4(0.f, 0.f, 0.f, 0.f);
    float4 a1 = a0, a2 = a0, a3 = a0;

    __shared__ int sidx[256];
    for (int base = s0; base < s1; base += 256) {
        int nn = min(256, s1 - base);
        if (tid < nn) sidx[tid] = g_order[base + tid];
        __syncthreads();
        int j = 0;
        for (; j + 4 <= nn; j += 4) {
            int i0 = sidx[j], i1 = sidx[j + 1], i2 = sidx[j + 2], i3 = sidx[j + 3];
            float4 v0 = src[(size_t)i0 * 128 + q];
            float4 v1 = src[(size_t)i1 * 128 + q];
            float4 v2 = src[(size_t)i2 * 128 + q];
            float4 v3 = src[(size_t)i3 * 128 + q];
            f4add(a0, v0); f4add(a1, v1); f4add(a2, v2); f4add(a3, v3);
        }
        for (; j < nn; j++) {
            f4add(a0, src[(size_t)sidx[j] * 128 + q]);
        }
        __syncthreads();
    }
    f4add(a0, a1); f4add(a2, a3); f4add(a0, a2);

    float4* dst = reinterpret_cast<float4*>(g_partial);
    dst[(((size_t)s * 2 + m) * NC + c) * 128 + q] = a0;
}

// ---------------------------------------------------------------------------
__device__ __forceinline__ float smooth_l1(float d) {
    d = fabsf(d);
    return d < 1.0f ? 0.5f * d * d : d - 0.5f;
}

// K5: combine partials, per-element SmoothL1 weighted by count, reduce.
__global__ void loss_kernel(const float* __restrict__ centers,
                            float* __restrict__ out) {
    int gid = blockIdx.x * blockDim.x + threadIdx.x;
    float val = 0.0f;
    if (gid < NC * FD) {
        int c = gid >> 9;  // FD == 512
        float cnt = g_countsf[c];
        if (cnt > 0.0f) {
            float sum1 = 0.0f, sum2 = 0.0f;
            #pragma unroll
            for (int s = 0; s < SPLITS; s++) {
                sum1 += g_partial[((s * 2 + 0) * NC) * FD + gid];
                sum2 += g_partial[((s * 2 + 1) * NC) * FD + gid];
            }
            float ctr = centers[gid];
            float inv = 1.0f / cnt;
            float f1 = smooth_l1(sum1 * inv - ctr);
            float f2 = smooth_l1(sum2 * inv - ctr);
            val = cnt * (f1 + f2);
        }
    }
    for (int off = 32; off > 0; off >>= 1)
        val += __shfl_down(val, off, 64);
    __shared__ float wsum[4];
    int lane = threadIdx.x & 63;
    int wid = threadIdx.x >> 6;
    if (lane == 0) wsum[wid] = val;
    __syncthreads();
    if (threadIdx.x == 0) {
        float sm = wsum[0] + wsum[1] + wsum[2] + wsum[3];
        atomicAdd(out, sm * 5.9604644775390625e-08f);  // 1/(N*D) = 2^-24
    }
}

extern "C" void kernel_launch(void* const* d_in, const int* in_sizes, int n_in,
                              void* d_out, int out_size, void* d_ws, size_t ws_size,
                              hipStream_t stream) {
    const float4* m1 = (const float4*)d_in[0];
    const float4* m2 = (const float4*)d_in[1];
    const float* centers = (const float*)d_in[2];
    const int* targets = (const int*)d_in[3];
    float* out = (float*)d_out;

    hist_kernel<<<HB, HT, 0, stream>>>(targets);
    scan_kernel<<<1, 512, 0, stream>>>(out);
    scatter_kernel<<<(NS + 255) / 256, 256, 0, stream>>>(targets);
    gather_sum_kernel<<<NC * SPLITS, 256, 0, stream>>>(m1, m2);
    loss_kernel<<<(NC * FD + 255) / 256, 256, 0, stream>>>(centers, out);
}

// Round 4
// 176.379 us; speedup vs baseline: 3.4023x; 1.1026x over previous
//
#include <hip/hip_runtime.h>

#define NS 32768
#define NC 395
#define FD 512
#define SPLITS 8
#define CHUNK (NS / SPLITS)   // 4096 targets scanned per block
#define TPB 256

// Static device scratch — every slot rewritten each call.
// partial sums: [split][modality][class][dim]  (~13 MB)
__device__ float g_partial[SPLITS * 2 * NC * FD];
__device__ int   g_pcount[SPLITS * NC];   // per-(split,class) match counts

// ---------------------------------------------------------------------------
__device__ __forceinline__ void f4add(float4& a, const float4 b) {
    a.x += b.x; a.y += b.y; a.z += b.z; a.w += b.w;
}

// K1: one block per (class, split). Phase 1: scan the split's target slice,
// compact matching sample indices into LDS (few LDS atomics). Phase 2:
// threads 0-127 accumulate modality-1 quads, 128-255 modality-2 quads,
// registers only, zero global atomics. Writes partial sums + count.
__global__ void gather_sum_kernel(const float4* __restrict__ m1,
                                  const float4* __restrict__ m2,
                                  const int* __restrict__ targets,
                                  float* __restrict__ out) {
    int c   = blockIdx.x >> 3;    // class
    int s   = blockIdx.x & 7;     // split
    int tid = threadIdx.x;

    if (blockIdx.x == 0 && tid == 0) out[0] = 0.0f;  // zero before loss kernel

    __shared__ int sidx[CHUNK];   // worst case: whole chunk is one class (16 KB)
    __shared__ int scnt;
    if (tid == 0) scnt = 0;
    __syncthreads();

    // Phase 1: coalesced scan of 4096 targets (16 per thread, stride TPB).
    int base = s * CHUNK;
    #pragma unroll
    for (int k = 0; k < CHUNK / TPB; k++) {
        int i = base + k * TPB + tid;
        if (targets[i] == c) {
            int p = atomicAdd(&scnt, 1);   // LDS atomic, ~10 total per block
            sidx[p] = i;
        }
    }
    __syncthreads();
    int cnt = scnt;

    // Phase 2: row gather with register accumulation.
    int m = tid >> 7;             // modality (wave-uniform)
    int q = tid & 127;            // float4 quad within the 512-dim row
    const float4* src = m ? m2 : m1;

    float4 a0 = make_float4(0.f, 0.f, 0.f, 0.f);
    float4 a1 = a0, a2 = a0, a3 = a0;

    int j = 0;
    for (; j + 4 <= cnt; j += 4) {
        int i0 = sidx[j], i1 = sidx[j + 1], i2 = sidx[j + 2], i3 = sidx[j + 3];
        float4 v0 = src[(size_t)i0 * 128 + q];
        float4 v1 = src[(size_t)i1 * 128 + q];
        float4 v2 = src[(size_t)i2 * 128 + q];
        float4 v3 = src[(size_t)i3 * 128 + q];
        f4add(a0, v0); f4add(a1, v1); f4add(a2, v2); f4add(a3, v3);
    }
    for (; j < cnt; j++)
        f4add(a0, src[(size_t)sidx[j] * 128 + q]);
    f4add(a0, a1); f4add(a2, a3); f4add(a0, a2);

    // partial[s][m][c][q*4..] — always written (zeros if no matches).
    float4* dst = reinterpret_cast<float4*>(g_partial);
    dst[(((size_t)s * 2 + m) * NC + c) * 128 + q] = a0;
    if (tid == 0) g_pcount[s * NC + c] = cnt;
}

// ---------------------------------------------------------------------------
__device__ __forceinline__ float smooth_l1(float d) {
    d = fabsf(d);
    return d < 1.0f ? 0.5f * d * d : d - 0.5f;
}

// K2: combine partials + counts, per-element SmoothL1 weighted by count, reduce.
__global__ void loss_kernel(const float* __restrict__ centers,
                            float* __restrict__ out) {
    int gid = blockIdx.x * blockDim.x + threadIdx.x;
    float val = 0.0f;
    if (gid < NC * FD) {
        int c = gid >> 9;  // FD == 512
        int icnt = 0;
        #pragma unroll
        for (int s = 0; s < SPLITS; s++) icnt += g_pcount[s * NC + c];
        if (icnt > 0) {
            float sum1 = 0.0f, sum2 = 0.0f;
            #pragma unroll
            for (int s = 0; s < SPLITS; s++) {
                sum1 += g_partial[((s * 2 + 0) * NC) * FD + gid];
                sum2 += g_partial[((s * 2 + 1) * NC) * FD + gid];
            }
            float cnt = (float)icnt;
            float ctr = centers[gid];
            float inv = 1.0f / cnt;
            float f1 = smooth_l1(sum1 * inv - ctr);
            float f2 = smooth_l1(sum2 * inv - ctr);
            val = cnt * (f1 + f2);
        }
    }
    for (int off = 32; off > 0; off >>= 1)
        val += __shfl_down(val, off, 64);
    __shared__ float wsum[4];
    int lane = threadIdx.x & 63;
    int wid = threadIdx.x >> 6;
    if (lane == 0) wsum[wid] = val;
    __syncthreads();
    if (threadIdx.x == 0) {
        float sm = wsum[0] + wsum[1] + wsum[2] + wsum[3];
        atomicAdd(out, sm * 5.9604644775390625e-08f);  // 1/(N*D) = 2^-24
    }
}

extern "C" void kernel_launch(void* const* d_in, const int* in_sizes, int n_in,
                              void* d_out, int out_size, void* d_ws, size_t ws_size,
                              hipStream_t stream) {
    const float4* m1 = (const float4*)d_in[0];
    const float4* m2 = (const float4*)d_in[1];
    const float* centers = (const float*)d_in[2];
    const int* targets = (const int*)d_in[3];
    float* out = (float*)d_out;

    gather_sum_kernel<<<NC * SPLITS, TPB, 0, stream>>>(m1, m2, targets, out);
    loss_kernel<<<(NC * FD + 255) / 256, 256, 0, stream>>>(centers, out);
}